// Round 1
// baseline (4571.218 us; speedup 1.0000x reference)
//
#include <hip/hip_runtime.h>
#include <stdint.h>

#define DIMC 1536
#define LTOK 3072
#define HEADS 12
#define HD 128
#define FS 384            // H*W = 16*24
#define MAXATTN 1920

typedef __attribute__((ext_vector_type(4))) float f32x4;
typedef __attribute__((ext_vector_type(8))) short bf16x8;

__device__ __forceinline__ unsigned short f2bf(float f) {
  union { float f; unsigned int u; } c; c.f = f;
  unsigned int u = c.u + 0x7fffu + ((c.u >> 16) & 1u);   // RNE
  return (unsigned short)(u >> 16);
}
__device__ __forceinline__ float bflo(unsigned int u) {
  union { unsigned int u; float f; } c; c.u = u << 16; return c.f;
}
__device__ __forceinline__ float bfhi(unsigned int u) {
  union { unsigned int u; float f; } c; c.u = u & 0xffff0000u; return c.f;
}

// ---------------- fp32 -> bf16 conversion (vectorized x4) ----------------
__global__ void cvt_bf16_k(const float* __restrict__ in,
                           unsigned short* __restrict__ out, int n4) {
  int i = blockIdx.x * blockDim.x + threadIdx.x;
  if (i >= n4) return;
  float4 f = ((const float4*)in)[i];
  uint2 o;
  o.x = (unsigned int)f2bf(f.x) | ((unsigned int)f2bf(f.y) << 16);
  o.y = (unsigned int)f2bf(f.z) | ((unsigned int)f2bf(f.w) << 16);
  ((uint2*)out)[i] = o;
}

// ---------------- NT GEMM: C[M,N] = A[M,K] * B[N,K]^T + bias ----------------
// 128x128 tile, BK=32, 256 threads (4 waves, 2x2), 4x4 mfma_f32_16x16x32_bf16
// per wave. blockIdx.z selects among 3 weight/out sets (qkv fusion).
template <bool F32OUT>
__global__ __launch_bounds__(256)
void gemm_nt(const unsigned short* __restrict__ A,
             const unsigned short* __restrict__ B0,
             const unsigned short* __restrict__ B1,
             const unsigned short* __restrict__ B2,
             const float* __restrict__ bias0,
             const float* __restrict__ bias1,
             const float* __restrict__ bias2,
             void* __restrict__ o0, void* __restrict__ o1, void* __restrict__ o2)
{
  const int z = blockIdx.z;
  const unsigned short* Bw = (z == 0) ? B0 : (z == 1) ? B1 : B2;
  const float* bias = (z == 0) ? bias0 : (z == 1) ? bias1 : bias2;
  void* outp = (z == 0) ? o0 : (z == 1) ? o1 : o2;

  __shared__ __align__(16) unsigned short lA[128 * 32];
  __shared__ __align__(16) unsigned short lB[128 * 32];

  const int tid = threadIdx.x;
  const int wave = tid >> 6;
  const int lane = tid & 63;
  const int m0 = blockIdx.y * 128;
  const int n0 = blockIdx.x * 128;
  const int wm = (wave >> 1) * 64;   // wave row offset in tile
  const int wn = (wave & 1) * 64;    // wave col offset in tile

  f32x4 acc[4][4] = {};

  // staging map: thread t loads 8 contiguous bf16 (16B) per row-half
  const int srow = tid >> 2;         // 0..63
  const int scol = (tid & 3) * 8;    // elem offset 0,8,16,24
  // fragment map (A and B identical: K-major rows)
  const int fr = lane & 15;          // m (or n) within 16-tile
  const int fk = (lane >> 4) * 8;    // k offset of this lane's 8 elems

  for (int k0 = 0; k0 < DIMC; k0 += 32) {
    uint4 a0 = *(const uint4*)(A  + (size_t)(m0 + srow)      * DIMC + k0 + scol);
    uint4 a1 = *(const uint4*)(A  + (size_t)(m0 + srow + 64) * DIMC + k0 + scol);
    uint4 b0 = *(const uint4*)(Bw + (size_t)(n0 + srow)      * DIMC + k0 + scol);
    uint4 b1 = *(const uint4*)(Bw + (size_t)(n0 + srow + 64) * DIMC + k0 + scol);
    *(uint4*)&lA[srow * 32 + scol]        = a0;
    *(uint4*)&lA[(srow + 64) * 32 + scol] = a1;
    *(uint4*)&lB[srow * 32 + scol]        = b0;
    *(uint4*)&lB[(srow + 64) * 32 + scol] = b1;
    __syncthreads();

    bf16x8 af[4], bf[4];
#pragma unroll
    for (int i = 0; i < 4; ++i)
      af[i] = *(const bf16x8*)&lA[(wm + i * 16 + fr) * 32 + fk];
#pragma unroll
    for (int j = 0; j < 4; ++j)
      bf[j] = *(const bf16x8*)&lB[(wn + j * 16 + fr) * 32 + fk];
#pragma unroll
    for (int i = 0; i < 4; ++i)
#pragma unroll
      for (int j = 0; j < 4; ++j)
        acc[i][j] = __builtin_amdgcn_mfma_f32_16x16x32_bf16(af[i], bf[j], acc[i][j], 0, 0, 0);
    __syncthreads();
  }

  // epilogue: C/D layout col=lane&15, row=(lane>>4)*4+reg
  const int col = lane & 15;
  const int rb = (lane >> 4) * 4;
#pragma unroll
  for (int j = 0; j < 4; ++j) {
    const int gn = n0 + wn + j * 16 + col;
    const float bv = bias[gn];
#pragma unroll
    for (int i = 0; i < 4; ++i) {
#pragma unroll
      for (int r = 0; r < 4; ++r) {
        const int gm = m0 + wm + i * 16 + rb + r;
        float val = acc[i][j][r] + bv;
        if (F32OUT)
          ((float*)outp)[(size_t)gm * DIMC + gn] = val;
        else
          ((unsigned short*)outp)[(size_t)gm * DIMC + gn] = f2bf(val);
      }
    }
  }
}

// ---------------- rmsnorm (over full DIM) + 3D RoPE, in place ----------------
// grid: (LTOK, 2) ; block 256 ; thread owns 6 contiguous elems (3 pairs)
__global__ __launch_bounds__(256)
void rms_rope_k(unsigned short* __restrict__ q, unsigned short* __restrict__ k,
                const float* __restrict__ nqw, const float* __restrict__ nkw,
                const float* __restrict__ freqs)
{
  const int tok = blockIdx.x;
  const int which = blockIdx.y;
  unsigned short* row = (which ? k : q) + (size_t)tok * DIMC;
  const float* nw = which ? nkw : nqw;
  const int tid = threadIdx.x;
  const int base = tid * 6;

  float v[6];
  float ss = 0.f;
#pragma unroll
  for (int j = 0; j < 6; ++j) {
    union { unsigned int u; float f; } c;
    c.u = (unsigned int)row[base + j] << 16;
    v[j] = c.f;
    ss += c.f * c.f;
  }
#pragma unroll
  for (int off = 1; off < 64; off <<= 1) ss += __shfl_xor(ss, off);
  __shared__ float wsum[4];
  if ((tid & 63) == 0) wsum[tid >> 6] = ss;
  __syncthreads();
  const float total = wsum[0] + wsum[1] + wsum[2] + wsum[3];
  const float rms = rsqrtf(total * (1.f / DIMC) + 1e-6f);

  const int f = tok / FS;
  const int rem = tok - f * FS;
  const int h = rem / 24;
  const int w = rem - h * 24;

#pragma unroll
  for (int pp = 0; pp < 3; ++pp) {
    const int P = (base >> 1) + pp;   // global pair index
    const int p = P & 63;             // pair within head
    const int t = (p < 22) ? f : ((p < 43) ? h : w);
    const float fr = freqs[t * 128 + p * 2];
    const float fi = freqs[t * 128 + p * 2 + 1];
    const float e = v[2 * pp]     * rms * nw[base + 2 * pp];
    const float o = v[2 * pp + 1] * rms * nw[base + 2 * pp + 1];
    row[base + 2 * pp]     = f2bf(e * fr - o * fi);
    row[base + 2 * pp + 1] = f2bf(e * fi + o * fr);
  }
}

// ---------------- attention: one wave per (query, head) ----------------
// key set = [0,384) U [max(0,(qf+1)*384-1920), (qf+1)*384)  (contiguous ranges)
__global__ __launch_bounds__(256)
void attn_k(const unsigned short* __restrict__ q,
            const unsigned short* __restrict__ k,
            const unsigned short* __restrict__ v,
            unsigned short* __restrict__ o)
{
  const int wave = threadIdx.x >> 6;
  const int lane = threadIdx.x & 63;
  const int tok = blockIdx.x * 4 + wave;
  const int head = blockIdx.y;
  const size_t doff = (size_t)head * HD + lane * 2;

  const unsigned int qraw = *(const unsigned int*)(q + (size_t)tok * DIMC + doff);
  // fold 1/sqrt(128) and log2(e) into q so softmax runs in exp2 domain
  const float cs = 0.08838834764831845f * 1.4426950408889634f;
  const float q0 = bflo(qraw) * cs;
  const float q1 = bfhi(qraw) * cs;

  const int qf = tok / FS;
  const int kend = (qf + 1) * FS;
  const int s2 = kend - MAXATTN;

  float m = -3.0e38f, l = 0.f, a0 = 0.f, a1 = 0.f;

  auto step = [&](int j) {
    const size_t off = (size_t)j * DIMC + doff;
    const unsigned int kraw = *(const unsigned int*)(k + off);
    float d = q0 * bflo(kraw) + q1 * bfhi(kraw);
#pragma unroll
    for (int t = 1; t < 64; t <<= 1) d += __shfl_xor(d, t);
    const unsigned int vraw = *(const unsigned int*)(v + off);
    const float v0 = bflo(vraw), v1 = bfhi(vraw);
    if (d > m) {            // wave-uniform branch (d identical on all lanes)
      const float al = exp2f(m - d);
      l = l * al + 1.f;
      a0 = a0 * al + v0;
      a1 = a1 * al + v1;
      m = d;
    } else {
      const float p = exp2f(d - m);
      l += p;
      a0 += p * v0;
      a1 += p * v1;
    }
  };

  if (s2 <= FS) {
    for (int j = 0; j < kend; ++j) step(j);
  } else {
    for (int j = 0; j < FS; ++j) step(j);
    for (int j = s2; j < kend; ++j) step(j);
  }

  const float inv = 1.f / l;
  const unsigned int pack =
      (unsigned int)f2bf(a0 * inv) | ((unsigned int)f2bf(a1 * inv) << 16);
  *(unsigned int*)(o + (size_t)tok * DIMC + doff) = pack;
}

// ---------------- launch ----------------
extern "C" void kernel_launch(void* const* d_in, const int* in_sizes, int n_in,
                              void* d_out, int out_size, void* d_ws, size_t ws_size,
                              hipStream_t stream)
{
  (void)in_sizes; (void)n_in; (void)out_size; (void)ws_size;
  const float* x     = (const float*)d_in[0];
  const float* freqs = (const float*)d_in[3];
  const float* wq    = (const float*)d_in[4];
  const float* bq    = (const float*)d_in[5];
  const float* wk    = (const float*)d_in[6];
  const float* bk    = (const float*)d_in[7];
  const float* wv    = (const float*)d_in[8];
  const float* bv    = (const float*)d_in[9];
  const float* wo    = (const float*)d_in[10];
  const float* bo    = (const float*)d_in[11];
  const float* nqw   = (const float*)d_in[12];
  const float* nkw   = (const float*)d_in[13];

  char* ws = (char*)d_ws;
  size_t off = 0;
  auto take = [&](size_t bytes) -> void* {
    void* p = ws + off; off += (bytes + 255) & ~(size_t)255; return p;
  };
  unsigned short* xb  = (unsigned short*)take((size_t)LTOK * DIMC * 2);
  unsigned short* wqb = (unsigned short*)take((size_t)DIMC * DIMC * 2);
  unsigned short* wkb = (unsigned short*)take((size_t)DIMC * DIMC * 2);
  unsigned short* wvb = (unsigned short*)take((size_t)DIMC * DIMC * 2);
  unsigned short* wob = (unsigned short*)take((size_t)DIMC * DIMC * 2);
  unsigned short* qb  = (unsigned short*)take((size_t)LTOK * DIMC * 2);
  unsigned short* kb  = (unsigned short*)take((size_t)LTOK * DIMC * 2);
  unsigned short* vb  = (unsigned short*)take((size_t)LTOK * DIMC * 2);
  unsigned short* ab  = (unsigned short*)take((size_t)LTOK * DIMC * 2);

  const int xe4 = LTOK * DIMC / 4;
  const int we4 = DIMC * DIMC / 4;
  cvt_bf16_k<<<dim3((xe4 + 255) / 256), dim3(256), 0, stream>>>(x, xb, xe4);
  cvt_bf16_k<<<dim3((we4 + 255) / 256), dim3(256), 0, stream>>>(wq, wqb, we4);
  cvt_bf16_k<<<dim3((we4 + 255) / 256), dim3(256), 0, stream>>>(wk, wkb, we4);
  cvt_bf16_k<<<dim3((we4 + 255) / 256), dim3(256), 0, stream>>>(wv, wvb, we4);
  cvt_bf16_k<<<dim3((we4 + 255) / 256), dim3(256), 0, stream>>>(wo, wob, we4);

  gemm_nt<false><<<dim3(DIMC / 128, LTOK / 128, 3), dim3(256), 0, stream>>>(
      xb, wqb, wkb, wvb, bq, bk, bv, qb, kb, vb);

  rms_rope_k<<<dim3(LTOK, 2), dim3(256), 0, stream>>>(qb, kb, nqw, nkw, freqs);

  attn_k<<<dim3(LTOK / 4, HEADS), dim3(256), 0, stream>>>(qb, kb, vb, ab);

  gemm_nt<true><<<dim3(DIMC / 128, LTOK / 128, 1), dim3(256), 0, stream>>>(
      ab, wob, wob, wob, bo, bo, bo, d_out, d_out, d_out);
}

// Round 2
// 428.801 us; speedup vs baseline: 10.6605x; 10.6605x over previous
//
#include <hip/hip_runtime.h>
#include <stdint.h>

#define DIMC 1536
#define LTOK 3072
#define HEADS 12
#define HD 128
#define FS 384            // H*W = 16*24
#define MAXATTN 1920

typedef __attribute__((ext_vector_type(4))) float f32x4;
typedef __attribute__((ext_vector_type(8))) short bf16x8;

__device__ __forceinline__ unsigned short f2bf(float f) {
  union { float f; unsigned int u; } c; c.f = f;
  unsigned int u = c.u + 0x7fffu + ((c.u >> 16) & 1u);   // RNE
  return (unsigned short)(u >> 16);
}
__device__ __forceinline__ float bflo(unsigned int u) {
  union { unsigned int u; float f; } c; c.u = u << 16; return c.f;
}
__device__ __forceinline__ float bfhi(unsigned int u) {
  union { unsigned int u; float f; } c; c.u = u & 0xffff0000u; return c.f;
}
__device__ __forceinline__ float bf2f(unsigned short s) {
  union { unsigned int u; float f; } c; c.u = (unsigned int)s << 16; return c.f;
}

// ---------------- fp32 -> bf16 conversion (vectorized x4) ----------------
__global__ void cvt_bf16_k(const float* __restrict__ in,
                           unsigned short* __restrict__ out, int n4) {
  int i = blockIdx.x * blockDim.x + threadIdx.x;
  if (i >= n4) return;
  float4 f = ((const float4*)in)[i];
  uint2 o;
  o.x = (unsigned int)f2bf(f.x) | ((unsigned int)f2bf(f.y) << 16);
  o.y = (unsigned int)f2bf(f.z) | ((unsigned int)f2bf(f.w) << 16);
  ((uint2*)out)[i] = o;
}

// ---------------- NT GEMM: C[M,N] = A[M,K] * B[N,K]^T + bias ----------------
template <bool F32OUT>
__global__ __launch_bounds__(256)
void gemm_nt(const unsigned short* __restrict__ A,
             const unsigned short* __restrict__ B0,
             const unsigned short* __restrict__ B1,
             const unsigned short* __restrict__ B2,
             const float* __restrict__ bias0,
             const float* __restrict__ bias1,
             const float* __restrict__ bias2,
             void* __restrict__ o0, void* __restrict__ o1, void* __restrict__ o2)
{
  const int z = blockIdx.z;
  const unsigned short* Bw = (z == 0) ? B0 : (z == 1) ? B1 : B2;
  const float* bias = (z == 0) ? bias0 : (z == 1) ? bias1 : bias2;
  void* outp = (z == 0) ? o0 : (z == 1) ? o1 : o2;

  __shared__ __align__(16) unsigned short lA[128 * 32];
  __shared__ __align__(16) unsigned short lB[128 * 32];

  const int tid = threadIdx.x;
  const int wave = tid >> 6;
  const int lane = tid & 63;
  const int m0 = blockIdx.y * 128;
  const int n0 = blockIdx.x * 128;
  const int wm = (wave >> 1) * 64;
  const int wn = (wave & 1) * 64;

  f32x4 acc[4][4] = {};

  const int srow = tid >> 2;
  const int scol = (tid & 3) * 8;
  const int fr = lane & 15;
  const int fk = (lane >> 4) * 8;

  for (int k0 = 0; k0 < DIMC; k0 += 32) {
    uint4 a0 = *(const uint4*)(A  + (size_t)(m0 + srow)      * DIMC + k0 + scol);
    uint4 a1 = *(const uint4*)(A  + (size_t)(m0 + srow + 64) * DIMC + k0 + scol);
    uint4 b0 = *(const uint4*)(Bw + (size_t)(n0 + srow)      * DIMC + k0 + scol);
    uint4 b1 = *(const uint4*)(Bw + (size_t)(n0 + srow + 64) * DIMC + k0 + scol);
    *(uint4*)&lA[srow * 32 + scol]        = a0;
    *(uint4*)&lA[(srow + 64) * 32 + scol] = a1;
    *(uint4*)&lB[srow * 32 + scol]        = b0;
    *(uint4*)&lB[(srow + 64) * 32 + scol] = b1;
    __syncthreads();

    bf16x8 af[4], bf[4];
#pragma unroll
    for (int i = 0; i < 4; ++i)
      af[i] = *(const bf16x8*)&lA[(wm + i * 16 + fr) * 32 + fk];
#pragma unroll
    for (int j = 0; j < 4; ++j)
      bf[j] = *(const bf16x8*)&lB[(wn + j * 16 + fr) * 32 + fk];
#pragma unroll
    for (int i = 0; i < 4; ++i)
#pragma unroll
      for (int j = 0; j < 4; ++j)
        acc[i][j] = __builtin_amdgcn_mfma_f32_16x16x32_bf16(af[i], bf[j], acc[i][j], 0, 0, 0);
    __syncthreads();
  }

  const int col = lane & 15;
  const int rb = (lane >> 4) * 4;
#pragma unroll
  for (int j = 0; j < 4; ++j) {
    const int gn = n0 + wn + j * 16 + col;
    const float bv = bias[gn];
#pragma unroll
    for (int i = 0; i < 4; ++i) {
#pragma unroll
      for (int r = 0; r < 4; ++r) {
        const int gm = m0 + wm + i * 16 + rb + r;
        float val = acc[i][j][r] + bv;
        if (F32OUT)
          ((float*)outp)[(size_t)gm * DIMC + gn] = val;
        else
          ((unsigned short*)outp)[(size_t)gm * DIMC + gn] = f2bf(val);
      }
    }
  }
}

// ---------------- rmsnorm + 3D RoPE, in place ----------------
__global__ __launch_bounds__(256)
void rms_rope_k(unsigned short* __restrict__ q, unsigned short* __restrict__ k,
                const float* __restrict__ nqw, const float* __restrict__ nkw,
                const float* __restrict__ freqs)
{
  const int tok = blockIdx.x;
  const int which = blockIdx.y;
  unsigned short* row = (which ? k : q) + (size_t)tok * DIMC;
  const float* nw = which ? nkw : nqw;
  const int tid = threadIdx.x;
  const int base = tid * 6;

  float v[6];
  float ss = 0.f;
#pragma unroll
  for (int j = 0; j < 6; ++j) {
    v[j] = bf2f(row[base + j]);
    ss += v[j] * v[j];
  }
#pragma unroll
  for (int off = 1; off < 64; off <<= 1) ss += __shfl_xor(ss, off);
  __shared__ float wsum[4];
  if ((tid & 63) == 0) wsum[tid >> 6] = ss;
  __syncthreads();
  const float total = wsum[0] + wsum[1] + wsum[2] + wsum[3];
  const float rms = rsqrtf(total * (1.f / DIMC) + 1e-6f);

  const int f = tok / FS;
  const int rem = tok - f * FS;
  const int h = rem / 24;
  const int w = rem - h * 24;

#pragma unroll
  for (int pp = 0; pp < 3; ++pp) {
    const int P = (base >> 1) + pp;
    const int p = P & 63;
    const int t = (p < 22) ? f : ((p < 43) ? h : w);
    const float fr = freqs[t * 128 + p * 2];
    const float fi = freqs[t * 128 + p * 2 + 1];
    const float e = v[2 * pp]     * rms * nw[base + 2 * pp];
    const float o = v[2 * pp + 1] * rms * nw[base + 2 * pp + 1];
    row[base + 2 * pp]     = f2bf(e * fr - o * fi);
    row[base + 2 * pp + 1] = f2bf(e * fi + o * fr);
  }
}

// ---------------- V transpose: vt[d][tok] = v[tok][d] ----------------
// tile 64 tok x 64 dim; grid (48, 24), block 256
__global__ __launch_bounds__(256)
void transpose_v_k(const unsigned short* __restrict__ v,
                   unsigned short* __restrict__ vt)
{
  __shared__ __align__(16) unsigned short t[64 * 72];  // [dim][tok], stride 72
  const int tb = blockIdx.x * 64;
  const int db = blockIdx.y * 64;
  const int tid = threadIdx.x;
#pragma unroll
  for (int it = 0; it < 2; ++it) {
    int c = tid + it * 256;           // 0..511
    int tok = c >> 3, dc = (c & 7) * 8;
    uint4 val = *(const uint4*)(v + (size_t)(tb + tok) * DIMC + db + dc);
    unsigned short tmp[8];
    *(uint4*)tmp = val;
#pragma unroll
    for (int j = 0; j < 8; ++j) t[(dc + j) * 72 + tok] = tmp[j];
  }
  __syncthreads();
#pragma unroll
  for (int it = 0; it < 2; ++it) {
    int c = tid + it * 256;
    int d = c >> 3, tc = (c & 7) * 8;
    *(uint4*)(vt + ((size_t)db + d) * LTOK + tb + tc) = *(const uint4*)&t[d * 72 + tc];
  }
}

// ---------------- MFMA flash attention ----------------
// grid: 576 blocks (48 q-blocks x 12 heads, heavy frames first), 256 threads.
// WG = 64 queries (4 waves x 16) of one head; key tiles of 64.
// Key set = [0,384) U [kend-1920, kend) -- all boundaries multiples of 64,
// so no per-element masking, only tile-range bounds.
__global__ __launch_bounds__(256)
void attn_mfma(const unsigned short* __restrict__ q,
               const unsigned short* __restrict__ k,
               const unsigned short* __restrict__ vt,
               unsigned short* __restrict__ o)
{
  const int head = blockIdx.x % HEADS;
  const int qb = 47 - blockIdx.x / HEADS;   // heavy (high qf) first
  const int q0 = qb * 64;
  const int qf = q0 / FS;

  const int wave = threadIdx.x >> 6;
  const int lane = threadIdx.x & 63;
  const int col = lane & 15;          // frag row index / C-layout col
  const int rb4 = (lane >> 4) * 4;    // C-layout row base
  const int kf8 = (lane >> 4) * 8;    // frag k offset

  __shared__ __align__(16) unsigned short Kl[64 * 136];   // [key][dim]
  __shared__ __align__(16) unsigned short Vtl[128 * 72];  // [d][key]
  __shared__ __align__(16) unsigned short Pl[4][16 * 72]; // per-wave [q][key]
  __shared__ float alf[4][16];
  __shared__ float lif[4][16];

  // Q fragments: A[m=q][k=dim], 4 frags cover HD=128
  bf16x8 qfrag[4];
  {
    const unsigned short* qrow = q + (size_t)(q0 + wave * 16 + col) * DIMC + head * HD;
#pragma unroll
    for (int kk = 0; kk < 4; ++kk)
      qfrag[kk] = *(const bf16x8*)(qrow + kk * 32 + kf8);
  }

  f32x4 oacc[8] = {};    // O^T tiles: [d-tile], C col = q, row = d
  float m[4], l[4];
#pragma unroll
  for (int r = 0; r < 4; ++r) { m[r] = -3.0e38f; l[r] = 0.f; }

  const float cs = 0.08838834764831845f * 1.4426950408889634f; // scale*log2e

  const int kend = (qf + 1) * FS;
  const int nt1 = ((qf <= 5) ? kend : FS) / 64;
  const int s2 = kend - MAXATTN;
  const int nt = nt1 + ((qf <= 5) ? 0 : MAXATTN / 64);

  for (int t = 0; t < nt; ++t) {
    const int kbase = (t < nt1) ? t * 64 : s2 + (t - nt1) * 64;

    __syncthreads();   // previous tile's LDS reads complete
    {
      const int tid = threadIdx.x;
#pragma unroll
      for (int it = 0; it < 4; ++it) {
        const int c = tid + it * 256;           // 0..1023
        const int krow = c >> 4, kcl = (c & 15) * 8;
        *(uint4*)&Kl[krow * 136 + kcl] =
            *(const uint4*)(k + (size_t)(kbase + krow) * DIMC + head * HD + kcl);
        const int d = c >> 3, tk = (c & 7) * 8;
        *(uint4*)&Vtl[d * 72 + tk] =
            *(const uint4*)(vt + ((size_t)head * HD + d) * LTOK + kbase + tk);
      }
    }
    __syncthreads();

    // S = Q K^T  (C: col=key, row=query)
    f32x4 s[4] = {};
#pragma unroll
    for (int kt = 0; kt < 4; ++kt)
#pragma unroll
      for (int kk = 0; kk < 4; ++kk) {
        bf16x8 kfrag = *(const bf16x8*)&Kl[(kt * 16 + col) * 136 + kk * 32 + kf8];
        s[kt] = __builtin_amdgcn_mfma_f32_16x16x32_bf16(qfrag[kk], kfrag, s[kt], 0, 0, 0);
      }

    // online softmax per query row r
    float al[4];
#pragma unroll
    for (int r = 0; r < 4; ++r) {
      float t0 = fmaxf(fmaxf(s[0][r], s[1][r]), fmaxf(s[2][r], s[3][r]));
#pragma unroll
      for (int off = 1; off < 16; off <<= 1) t0 = fmaxf(t0, __shfl_xor(t0, off));
      t0 *= cs;
      const float mn = fmaxf(m[r], t0);
      al[r] = exp2f(m[r] - mn);
      m[r] = mn;
      float rs = 0.f;
#pragma unroll
      for (int kt = 0; kt < 4; ++kt) {
        const float p = exp2f(s[kt][r] * cs - mn);
        const unsigned short pb = f2bf(p);
        Pl[wave][(rb4 + r) * 72 + kt * 16 + col] = pb;
        rs += bf2f(pb);            // sum the rounded value (matches PV)
      }
#pragma unroll
      for (int off = 1; off < 16; off <<= 1) rs += __shfl_xor(rs, off);
      l[r] = l[r] * al[r] + rs;
    }

    if (col == 0) {
#pragma unroll
      for (int r = 0; r < 4; ++r) alf[wave][rb4 + r] = al[r];
    }
    const float aq = alf[wave][col];   // same-wave LDS RAW; lgkmcnt handles
#pragma unroll
    for (int dt = 0; dt < 8; ++dt)
#pragma unroll
      for (int r = 0; r < 4; ++r) oacc[dt][r] *= aq;

    // O^T += Vt * P^T : A row = d (from Vtl), B row = q (from Pl)
#pragma unroll
    for (int step = 0; step < 2; ++step) {
      bf16x8 pf = *(const bf16x8*)&Pl[wave][col * 72 + step * 32 + kf8];
#pragma unroll
      for (int dt = 0; dt < 8; ++dt) {
        bf16x8 vf = *(const bf16x8*)&Vtl[(dt * 16 + col) * 72 + step * 32 + kf8];
        oacc[dt] = __builtin_amdgcn_mfma_f32_16x16x32_bf16(vf, pf, oacc[dt], 0, 0, 0);
      }
    }
  }

  if (col == 0) {
#pragma unroll
    for (int r = 0; r < 4; ++r) lif[wave][rb4 + r] = 1.f / l[r];
  }
  const float linv = lif[wave][col];

  unsigned short* orow = o + (size_t)(q0 + wave * 16 + col) * DIMC + head * HD;
#pragma unroll
  for (int dt = 0; dt < 8; ++dt) {
    uint2 pk;
    pk.x = (unsigned int)f2bf(oacc[dt][0] * linv) | ((unsigned int)f2bf(oacc[dt][1] * linv) << 16);
    pk.y = (unsigned int)f2bf(oacc[dt][2] * linv) | ((unsigned int)f2bf(oacc[dt][3] * linv) << 16);
    *(uint2*)(orow + dt * 16 + rb4) = pk;
  }
}

// ---------------- launch ----------------
extern "C" void kernel_launch(void* const* d_in, const int* in_sizes, int n_in,
                              void* d_out, int out_size, void* d_ws, size_t ws_size,
                              hipStream_t stream)
{
  (void)in_sizes; (void)n_in; (void)out_size; (void)ws_size;
  const float* x     = (const float*)d_in[0];
  const float* freqs = (const float*)d_in[3];
  const float* wq    = (const float*)d_in[4];
  const float* bq    = (const float*)d_in[5];
  const float* wk    = (const float*)d_in[6];
  const float* bk    = (const float*)d_in[7];
  const float* wv    = (const float*)d_in[8];
  const float* bv    = (const float*)d_in[9];
  const float* wo    = (const float*)d_in[10];
  const float* bo    = (const float*)d_in[11];
  const float* nqw   = (const float*)d_in[12];
  const float* nkw   = (const float*)d_in[13];

  char* ws = (char*)d_ws;
  size_t off = 0;
  auto take = [&](size_t bytes) -> void* {
    void* p = ws + off; off += (bytes + 255) & ~(size_t)255; return p;
  };
  unsigned short* xb  = (unsigned short*)take((size_t)LTOK * DIMC * 2);
  unsigned short* wqb = (unsigned short*)take((size_t)DIMC * DIMC * 2);
  unsigned short* wkb = (unsigned short*)take((size_t)DIMC * DIMC * 2);
  unsigned short* wvb = (unsigned short*)take((size_t)DIMC * DIMC * 2);
  unsigned short* wob = (unsigned short*)take((size_t)DIMC * DIMC * 2);
  unsigned short* qb  = (unsigned short*)take((size_t)LTOK * DIMC * 2);
  unsigned short* kb  = (unsigned short*)take((size_t)LTOK * DIMC * 2);
  unsigned short* vb  = (unsigned short*)take((size_t)LTOK * DIMC * 2);
  unsigned short* ab  = (unsigned short*)take((size_t)LTOK * DIMC * 2);
  unsigned short* vtb = (unsigned short*)take((size_t)LTOK * DIMC * 2);

  const int xe4 = LTOK * DIMC / 4;
  const int we4 = DIMC * DIMC / 4;
  cvt_bf16_k<<<dim3((xe4 + 255) / 256), dim3(256), 0, stream>>>(x, xb, xe4);
  cvt_bf16_k<<<dim3((we4 + 255) / 256), dim3(256), 0, stream>>>(wq, wqb, we4);
  cvt_bf16_k<<<dim3((we4 + 255) / 256), dim3(256), 0, stream>>>(wk, wkb, we4);
  cvt_bf16_k<<<dim3((we4 + 255) / 256), dim3(256), 0, stream>>>(wv, wvb, we4);
  cvt_bf16_k<<<dim3((we4 + 255) / 256), dim3(256), 0, stream>>>(wo, wob, we4);

  gemm_nt<false><<<dim3(DIMC / 128, LTOK / 128, 3), dim3(256), 0, stream>>>(
      xb, wqb, wkb, wvb, bq, bk, bv, qb, kb, vb);

  rms_rope_k<<<dim3(LTOK, 2), dim3(256), 0, stream>>>(qb, kb, nqw, nkw, freqs);
  transpose_v_k<<<dim3(LTOK / 64, DIMC / 64), dim3(256), 0, stream>>>(vb, vtb);

  attn_mfma<<<dim3(48 * HEADS), dim3(256), 0, stream>>>(qb, kb, vtb, ab);

  gemm_nt<true><<<dim3(DIMC / 128, LTOK / 128, 1), dim3(256), 0, stream>>>(
      ab, wob, wob, wob, bo, bo, bo, d_out, d_out, d_out);
}